// Round 2
// baseline (617.068 us; speedup 1.0000x reference)
//
#include <hip/hip_runtime.h>
#include <hip/hip_bf16.h>
#include <cstdint>
#include <cstddef>

#define DIM 1024
#define B_SZ 32
#define L_SZ 2048

#define BM 128
#define BN 128

// pre_kernel block-range split
#define CVT_BLOCKS 8192
#define HT_BLOCKS  512
#define WA_BLOCKS  512

typedef __attribute__((ext_vector_type(8))) short bf16x8;
typedef __attribute__((ext_vector_type(4))) float floatx4;

static __device__ __forceinline__ unsigned cvt2_bf16_rne(float a, float b) {
    unsigned ua = __builtin_bit_cast(unsigned, a);
    unsigned ub = __builtin_bit_cast(unsigned, b);
    ua = (ua + 0x7FFFu + ((ua >> 16) & 1u)) >> 16;
    ub = (ub + 0x7FFFu + ((ub >> 16) & 1u)) >> 16;
    return ua | (ub << 16);
}

static __device__ __forceinline__ float bf2f(unsigned u16) {
    return __builtin_bit_cast(float, u16 << 16);
}

// tanh(x) = 1 - 2/(e^{2x}+1)
static __device__ __forceinline__ float tanh_fast(float x) {
    float e = __expf(2.0f * x);
    return 1.0f - 2.0f * __builtin_amdgcn_rcpf(e + 1.0f);
}

// async global->LDS, 16B per lane; LDS dest = uniform base + lane*16
static __device__ __forceinline__ void gld_lds16(const void* g, void* lds) {
    __builtin_amdgcn_global_load_lds(
        (const __attribute__((address_space(1))) unsigned int*)g,
        (__attribute__((address_space(3))) unsigned int*)lds,
        16, 0, 0);
}

// compiler-invisible LDS read: we own ALL waitcnt ordering for these.
// addr = 32-bit LDS byte offset (low 32 bits of flat pointer to __shared__).
static __device__ __forceinline__ bf16x8 dsr128(unsigned addr) {
    bf16x8 r;
    asm volatile("ds_read_b128 %0, %1" : "=v"(r) : "v"(addr));
    return r;
}

#define VMCNT(n)  asm volatile("s_waitcnt vmcnt(" #n ")" ::: "memory")
#define SBAR()    asm volatile("s_barrier" ::: "memory")
// rule #18: lgkmcnt via asm needs a following sched_barrier(0) so MFMAs
// consuming the asm ds_read results are not hoisted above the wait.
#define WAITK()   do { asm volatile("s_waitcnt lgkmcnt(0)" ::: "memory"); \
                       __builtin_amdgcn_sched_barrier(0); } while (0)

// ---------------------------------------------------------------------------
// pre_kernel: ONE dispatch for {ctx fp32->bf16, ht_proj, Wa_s fp32->bf16,
// scores zero, weighted zero}. Branch is block-uniform (blockIdx split).
// (UNCHANGED again: gemm fix isolated; pre/post counters surface next round.)
// ---------------------------------------------------------------------------
__global__ __launch_bounds__(256) void pre_kernel(
    const float* __restrict__ x, const float* __restrict__ ctx,
    const float* __restrict__ Wa,
    unsigned short* __restrict__ ctxB, unsigned short* __restrict__ WaB,
    float* __restrict__ ht, float* __restrict__ scores,
    float* __restrict__ weighted)
{
    const int bid = blockIdx.x, t = threadIdx.x;

    if (bid < CVT_BLOCKS) {
        const long n8 = (long)B_SZ * L_SZ * DIM / 8;
        const long stride = (long)CVT_BLOCKS * 256;
        for (long i = (long)bid * 256 + t; i < n8; i += stride) {
            const float4 a = ((const float4*)ctx)[i * 2];
            const float4 b = ((const float4*)ctx)[i * 2 + 1];
            uint4 o;
            o.x = cvt2_bf16_rne(a.x, a.y);
            o.y = cvt2_bf16_rne(a.z, a.w);
            o.z = cvt2_bf16_rne(b.x, b.y);
            o.w = cvt2_bf16_rne(b.z, b.w);
            ((uint4*)ctxB)[i] = o;
        }
    } else if (bid < CVT_BLOCKS + HT_BLOCKS) {
        const int lb = bid - CVT_BLOCKS;
        const int gi = lb * 256 + t;
        if (gi < B_SZ * L_SZ) scores[gi] = 0.f;
        const int b = lb >> 4, kb = lb & 15;
        __shared__ float xs[DIM];
        for (int i = t; i < DIM; i += 256) xs[i] = x[b * DIM + i];
        __syncthreads();
        const int wave = t >> 6, lane = t & 63;
        const float4* xs4 = (const float4*)xs;
        for (int kk = 0; kk < 16; ++kk) {
            const int k = kb * 64 + wave * 16 + kk;
            const float4* wr = (const float4*)(Wa + (size_t)k * (2 * DIM));
            float s = 0.f;
            #pragma unroll
            for (int d = 0; d < DIM / 4; d += 64) {
                const float4 w4 = wr[d + lane];
                const float4 x4 = xs4[d + lane];
                s += w4.x * x4.x + w4.y * x4.y + w4.z * x4.z + w4.w * x4.w;
            }
            #pragma unroll
            for (int off = 32; off > 0; off >>= 1) s += __shfl_xor(s, off);
            if (lane == 0) ht[b * DIM + k] = s;
        }
    } else {
        const int lb = bid - CVT_BLOCKS - HT_BLOCKS;
        const int i = lb * 256 + t;
        if (i < B_SZ * DIM) weighted[i] = 0.f;
        const int k = i >> 7, dc = i & 127;
        const float* s = Wa + (size_t)k * (2 * DIM) + DIM + dc * 8;
        const float4 a = ((const float4*)s)[0];
        const float4 b4 = ((const float4*)s)[1];
        uint4 o;
        o.x = cvt2_bf16_rne(a.x, a.y);
        o.y = cvt2_bf16_rne(a.z, a.w);
        o.z = cvt2_bf16_rne(b4.x, b4.y);
        o.w = cvt2_bf16_rne(b4.z, b4.w);
        ((uint4*)(WaB + (size_t)k * DIM + dc * 8))[0] = o;
    }
}

// ---------------------------------------------------------------------------
// 8-phase 256x256xBK64 bf16 GEMM, round 2: frag reads converted to inline-asm
// ds_read_b128 so the compiler's waitcnt pass cannot see any LDS reader and
// therefore cannot insert vmcnt(0) drains against the pending global_load_lds
// DMA (round-1 theory for why counted-vmcnt behaved like drain-0).
// All ordering is now explicit:
//   - asm s_barrier ("memory") pins staging issues into their phase
//   - WAITK (lgkmcnt(0)+sched_barrier(0)) between asm reads and MFMA (rule 18)
//   - counted VMCNT(2)@ph4 / VMCNT(4)@ph8 are the ONLY vmem waits in-loop
// B-fragments cached across phases (bvA h0, bvB h1): 48 ds_read/iter (=m201).
// Staging ~1 half-tile/phase; slot lifetime verified: every overwrite >=1 full
// phase after the slot's last read-issue; landing deadlines:
//   ph4 vmcnt(2) -> leaves As00(a+2) in flight, guarantees a+1 fully landed
//   ph8 vmcnt(4) -> leaves As10/Bs11(a+3) in flight, guarantees a+2 landed
// ---------------------------------------------------------------------------
static __device__ __forceinline__ void lda4(
    unsigned base, int wr, int l15, int quad, bf16x8 (&af)[4][2])
{
    #pragma unroll
    for (int i = 0; i < 4; ++i) {
        const int r = wr + i * 16 + l15;
        #pragma unroll
        for (int kb = 0; kb < 2; ++kb) {
            const int c = (kb * 4 + quad) ^ (r & 7);
            af[i][kb] = dsr128(base + (unsigned)(r * 128 + c * 16));
        }
    }
}

static __device__ __forceinline__ void ldb2(
    unsigned base, int wc, int l15, int quad, bf16x8 (&bv)[2][2])
{
    #pragma unroll
    for (int j = 0; j < 2; ++j) {
        const int r = wc + j * 16 + l15;
        #pragma unroll
        for (int kb = 0; kb < 2; ++kb) {
            const int c = (kb * 4 + quad) ^ (r & 7);
            bv[j][kb] = dsr128(base + (unsigned)(r * 128 + c * 16));
        }
    }
}

static __device__ __forceinline__ void mma16(
    floatx4 (&acc)[4][2], const bf16x8 (&af)[4][2], const bf16x8 (&bv)[2][2])
{
    __builtin_amdgcn_s_setprio(1);
    #pragma unroll
    for (int kb = 0; kb < 2; ++kb)
        #pragma unroll
        for (int i = 0; i < 4; ++i)
            #pragma unroll
            for (int j = 0; j < 2; ++j)
                acc[i][j] = __builtin_amdgcn_mfma_f32_16x16x32_bf16(
                    af[i][kb], bv[j][kb], acc[i][j], 0, 0, 0);
    __builtin_amdgcn_s_setprio(0);
}

// stage one half-tile (128 rows x 64 cols bf16 = 16KB) = 2 gld_lds16/thread.
// LDS dest linear in thread order; XOR swizzle applied on the GLOBAL source
// chunk so reads use the same XOR (both-sides-or-neither, rule 21).
static __device__ __forceinline__ void stage_half(
    const unsigned short* __restrict__ g, unsigned short* lds, int t, int wave)
{
    #pragma unroll
    for (int q = 0; q < 2; ++q) {
        const int ch = q * 512 + t;
        const int lr = ch >> 3;
        const int lc = (ch & 7) ^ (lr & 7);
        gld_lds16(g + (size_t)lr * DIM + lc * 8, lds + (q * 512 + wave * 64) * 8);
    }
}

__global__ __launch_bounds__(512, 2) void gemm_score_8ph(
    const unsigned short* __restrict__ A, const unsigned short* __restrict__ Bm,
    const float* __restrict__ Va, const float* __restrict__ ht,
    float* __restrict__ scores)
{
    __shared__ __align__(16) unsigned short As[2][2][128 * 64];
    __shared__ __align__(16) unsigned short Bs[2][2][128 * 64];

    // T1: XCD-aware swizzle (1024 blocks, 8 XCDs, bijective).
    const int bid = blockIdx.x;
    const int logical = (bid & 7) * 128 + (bid >> 3);
    const int m0 = (logical >> 2) * 256;
    const int n0 = (logical & 3) * 256;

    const int t = threadIdx.x;
    const int lane = t & 63, wave = t >> 6;
    const int l15 = lane & 15, quad = lane >> 4;
    const int wr = (wave >> 2) * 64;
    const int wc = (wave & 3) * 32;

    const unsigned short* Ag = A + (size_t)m0 * DIM;
    const unsigned short* Bg = Bm + (size_t)n0 * DIM;

    // 32-bit LDS byte offsets (low 32 bits of flat address of __shared__).
    const unsigned aB = (unsigned)(unsigned long long)&As[0][0][0];
    const unsigned bB = (unsigned)(unsigned long long)&Bs[0][0][0];
    // As[buf][half] stride = 128*64*2 = 16384 bytes
    const unsigned a00 = aB, a01 = aB + 16384, a10 = aB + 32768, a11 = aB + 49152;
    const unsigned b00 = bB, b01 = bB + 16384, b10 = bB + 32768, b11 = bB + 49152;

    floatx4 acc[4][4][2];   // [quadrant][i][j]
    #pragma unroll
    for (int q = 0; q < 4; ++q)
        #pragma unroll
        for (int i = 0; i < 4; ++i)
            #pragma unroll
            for (int j = 0; j < 2; ++j) acc[q][i][j] = (floatx4)0.f;

    bf16x8 af[4][2], bvA[2][2], bvB[2][2];

    // prologue: tile0 all 4 halves (buf0) + tile1 As10, Bs11 (the two halves
    // the steady-state loop stages at ph7/ph8 of the previous iter).
    stage_half(Ag, &As[0][0][0], t, wave);
    stage_half(Bg, &Bs[0][0][0], t, wave);
    stage_half(Bg + (size_t)128 * DIM, &Bs[0][1][0], t, wave);
    stage_half(Ag + (size_t)128 * DIM, &As[0][1][0], t, wave);
    stage_half(Ag + 64, &As[1][0][0], t, wave);
    stage_half(Bg + (size_t)128 * DIM + 64, &Bs[1][1][0], t, wave);
    VMCNT(4);               // buf0 landed; tile1's 2 halves stay in flight
    SBAR();

    for (int it = 0; it < 8; ++it) {            // 2 K-tiles (BK=64) per iter
        const int k1 = (2 * it + 1) * 64;
        const int k2 = (2 * it + 2) * 64;
        const int k3 = (2 * it + 3) * 64;
        const bool more = (it < 7);

        // ph1: q=(0,0) buf0; stage Bs10 <- a+1
        lda4(a00, wr, l15, quad, af);
        ldb2(b00, wc, l15, quad, bvA);
        stage_half(Bg + k1, &Bs[1][0][0], t, wave);
        SBAR();
        WAITK();
        mma16(acc[0], af, bvA);
        SBAR();

        // ph2: q=(0,1); stage As11 <- a+1, Bs00 <- a+2 (Bs00 last read ph1)
        ldb2(b01, wc, l15, quad, bvB);
        stage_half(Ag + (size_t)128 * DIM + k1, &As[1][1][0], t, wave);
        if (more) stage_half(Bg + k2, &Bs[0][0][0], t, wave);
        SBAR();
        WAITK();
        mma16(acc[1], af, bvB);
        SBAR();

        // ph3: q=(1,1) (bvB reused)
        lda4(a01, wr, l15, quad, af);
        SBAR();
        WAITK();
        mma16(acc[3], af, bvB);
        SBAR();

        // ph4: q=(1,0) (bvA cached from ph1, af from ph3 -- no new reads);
        // stage As00 <- a+2; vmcnt(2) leaves only As00 in flight => all of
        // tile a+1 (As10,Bs10,As11,Bs11) landed before ph5-8 read it.
        if (more) { stage_half(Ag + k2, &As[0][0][0], t, wave); VMCNT(2); }
        else      { VMCNT(0); }
        SBAR();
        mma16(acc[2], af, bvA);
        SBAR();

        // ph5: q=(0,0) buf1; stage Bs01 <- a+2
        lda4(a10, wr, l15, quad, af);
        ldb2(b10, wc, l15, quad, bvA);
        if (more) stage_half(Bg + (size_t)128 * DIM + k2, &Bs[0][1][0], t, wave);
        SBAR();
        WAITK();
        mma16(acc[0], af, bvA);
        SBAR();

        // ph6: q=(0,1); stage As01 <- a+2
        ldb2(b11, wc, l15, quad, bvB);
        if (more) stage_half(Ag + (size_t)128 * DIM + k2, &As[0][1][0], t, wave);
        SBAR();
        WAITK();
        mma16(acc[1], af, bvB);
        SBAR();

        // ph7: q=(1,1); stage As10 <- a+3 (As10 last read ph5)
        lda4(a11, wr, l15, quad, af);
        if (more) stage_half(Ag + k3, &As[1][0][0], t, wave);
        SBAR();
        WAITK();
        mma16(acc[3], af, bvB);
        SBAR();

        // ph8: q=(1,0) (bvA from ph5, af from ph7); stage Bs11 <- a+3;
        // vmcnt(4) leaves As10/Bs11 (a+3) in flight, guarantees a+2 landed
        // for next iter's ph1-4.
        if (more) {
            stage_half(Bg + (size_t)128 * DIM + k3, &Bs[1][1][0], t, wave);
            VMCNT(4);
        }
        SBAR();
        mma16(acc[2], af, bvA);
        SBAR();
    }

    // epilogue: scores[m] += sum_n tanh(acc + ht[n]) * Va[n]
    // C/D layout: n = lane&15, m = quad*4 + reg
    const int bb = m0 >> 11;
    float htv[2][2], vav[2][2];
    #pragma unroll
    for (int qc = 0; qc < 2; ++qc)
        #pragma unroll
        for (int j = 0; j < 2; ++j) {
            const int ng = n0 + qc * 128 + wc + j * 16 + l15;
            htv[qc][j] = ht[bb * DIM + ng];
            vav[qc][j] = Va[ng];
        }
    #pragma unroll
    for (int qr = 0; qr < 2; ++qr)
        #pragma unroll
        for (int i = 0; i < 4; ++i)
            #pragma unroll
            for (int r = 0; r < 4; ++r) {
                float s = 0.f;
                #pragma unroll
                for (int qc = 0; qc < 2; ++qc)
                    #pragma unroll
                    for (int j = 0; j < 2; ++j)
                        s += tanh_fast(acc[qr * 2 + qc][i][j][r] + htv[qc][j]) * vav[qc][j];
                s += __shfl_xor(s, 8);
                s += __shfl_xor(s, 4);
                s += __shfl_xor(s, 2);
                s += __shfl_xor(s, 1);
                if (l15 == 0)
                    atomicAdd(&scores[m0 + qr * 128 + wr + i * 16 + quad * 4 + r], s);
            }
}

// ---------------------------------------------------------------------------
// post_kernel: softmax (stats recomputed per block -- deterministic) + attn
// slice write + weighted slice accumulate from bf16 ctx. (UNCHANGED.)
// ---------------------------------------------------------------------------
__global__ __launch_bounds__(256) void post_kernel(
    const float* __restrict__ scores, const unsigned short* __restrict__ ctxB,
    float* __restrict__ attn, float* __restrict__ weighted)
{
    const int b = blockIdx.x, slice = blockIdx.y, t = threadIdx.x;
    const float* sc = scores + b * L_SZ;
    __shared__ float red[256];
    __shared__ float att[128];

    float m = -1e30f;
    for (int l = t; l < L_SZ; l += 256) m = fmaxf(m, sc[l]);
    red[t] = m; __syncthreads();
    for (int s = 128; s > 0; s >>= 1) { if (t < s) red[t] = fmaxf(red[t], red[t + s]); __syncthreads(); }
    m = red[0]; __syncthreads();
    float sum = 0.f;
    for (int l = t; l < L_SZ; l += 256) sum += __expf(sc[l] - m);
    red[t] = sum; __syncthreads();
    for (int s = 128; s > 0; s >>= 1) { if (t < s) red[t] += red[t + s]; __syncthreads(); }
    const float inv = 1.0f / red[0];

    const int l0 = slice * 128;
    if (t < 128) {
        const float av = __expf(sc[l0 + t] - m) * inv;
        att[t] = av;
        attn[b * L_SZ + l0 + t] = av;
    }
    __syncthreads();

    const unsigned short* cb = ctxB + ((size_t)b * L_SZ + l0) * DIM + t * 4;
    float a0 = 0.f, a1 = 0.f, a2 = 0.f, a3 = 0.f;
    for (int l = 0; l < 128; ++l) {
        const float a = att[l];
        const uint2 v = *(const uint2*)(cb + (size_t)l * DIM);
        a0 += a * bf2f(v.x & 0xFFFFu);
        a1 += a * bf2f(v.x >> 16);
        a2 += a * bf2f(v.y & 0xFFFFu);
        a3 += a * bf2f(v.y >> 16);
    }
    float* o = weighted + b * DIM + t * 4;
    atomicAdd(o + 0, a0);
    atomicAdd(o + 1, a1);
    atomicAdd(o + 2, a2);
    atomicAdd(o + 3, a3);
}

// ---------------------------------------------------------------------------
// fallback path (ws too small): fp32-staging GEMM + separate aux kernels
// ---------------------------------------------------------------------------
#define LDS_STRIDE 40
__global__ __launch_bounds__(256) void ht_kernel_fb(const float* __restrict__ x,
                                                    const float* __restrict__ Wa,
                                                    float* __restrict__ ht,
                                                    float* __restrict__ scores,
                                                    float* __restrict__ weighted) {
    const int b = blockIdx.x, kb = blockIdx.y, t = threadIdx.x;
    const int gidx = (b * 16 + kb) * 256 + t;
    if (gidx < B_SZ * L_SZ) scores[gidx] = 0.f;
    if (gidx < B_SZ * DIM) weighted[gidx] = 0.f;
    __shared__ float xs[DIM];
    for (int i = t; i < DIM; i += 256) xs[i] = x[b * DIM + i];
    __syncthreads();
    const int wave = t >> 6, lane = t & 63;
    for (int kk = 0; kk < 16; ++kk) {
        const int k = kb * 64 + wave * 16 + kk;
        const float* wr = Wa + (size_t)k * (2 * DIM);
        float s = 0.f;
        #pragma unroll
        for (int d = 0; d < DIM; d += 64) s += xs[d + lane] * wr[d + lane];
        #pragma unroll
        for (int off = 32; off > 0; off >>= 1) s += __shfl_xor(s, off);
        if (lane == 0) ht[b * DIM + k] = s;
    }
}

__global__ __launch_bounds__(256, 2) void gemm_score_kernel(
    const float* __restrict__ ctx, const float* __restrict__ Wa,
    const float* __restrict__ Va, const float* __restrict__ ht,
    float* __restrict__ scores)
{
    __shared__ unsigned short As[BM * LDS_STRIDE];
    __shared__ unsigned short Bs[BN * LDS_STRIDE];
    const int t = threadIdx.x;
    const int n0 = blockIdx.x * BN;
    const int m0 = blockIdx.y * BM;
    const int lane = t & 63, wave = t >> 6;
    const int l15 = lane & 15, quad = lane >> 4;
    const int wm = (wave >> 1) * 64, wn = (wave & 1) * 64;
    const int srow = t >> 3;
    const int scol = (t & 7) * 4;
    const float* aBase = ctx + (size_t)(m0 + srow) * DIM + scol;
    const float* bBase = Wa + (size_t)(n0 + srow) * (2 * DIM) + DIM + scol;

    floatx4 acc[4][4];
    #pragma unroll
    for (int i = 0; i < 4; ++i)
        #pragma unroll
        for (int j = 0; j < 4; ++j) acc[i][j] = (floatx4)0.f;

    for (int k0 = 0; k0 < DIM; k0 += 32) {
        __syncthreads();
        #pragma unroll
        for (int r = 0; r < 4; ++r) {
            const float4 va = *(const float4*)(aBase + (size_t)(r * 32) * DIM + k0);
            const float4 vb = *(const float4*)(bBase + (size_t)(r * 32) * (2 * DIM) + k0);
            *(uint2*)&As[(srow + r * 32) * LDS_STRIDE + scol] =
                make_uint2(cvt2_bf16_rne(va.x, va.y), cvt2_bf16_rne(va.z, va.w));
            *(uint2*)&Bs[(srow + r * 32) * LDS_STRIDE + scol] =
                make_uint2(cvt2_bf16_rne(vb.x, vb.y), cvt2_bf16_rne(vb.z, vb.w));
        }
        __syncthreads();
        bf16x8 af[4], bfr[4];
        #pragma unroll
        for (int i = 0; i < 4; ++i)
            af[i] = *(const bf16x8*)&As[(wm + i * 16 + l15) * LDS_STRIDE + quad * 8];
        #pragma unroll
        for (int j = 0; j < 4; ++j)
            bfr[j] = *(const bf16x8*)&Bs[(wn + j * 16 + l15) * LDS_STRIDE + quad * 8];
        #pragma unroll
        for (int i = 0; i < 4; ++i)
            #pragma unroll
            for (int j = 0; j < 4; ++j)
                acc[i][j] = __builtin_amdgcn_mfma_f32_16x16x32_bf16(af[i], bfr[j], acc[i][j], 0, 0, 0);
    }
    const int bb = m0 >> 11;
    float htv[4], vav[4];
    #pragma unroll
    for (int j = 0; j < 4; ++j) {
        const int ng = n0 + wn + j * 16 + l15;
        htv[j] = ht[bb * DIM + ng];
        vav[j] = Va[ng];
    }
    #pragma unroll
    for (int i = 0; i < 4; ++i) {
        #pragma unroll
        for (int r = 0; r < 4; ++r) {
            float s = 0.f;
            #pragma unroll
            for (int j = 0; j < 4; ++j)
                s += tanh_fast(acc[i][j][r] + htv[j]) * vav[j];
            s += __shfl_xor(s, 8);
            s += __shfl_xor(s, 4);
            s += __shfl_xor(s, 2);
            s += __shfl_xor(s, 1);
            if (l15 == 0)
                atomicAdd(&scores[m0 + wm + i * 16 + quad * 4 + r], s);
        }
    }
}

__global__ __launch_bounds__(256) void post_kernel_fb(
    const float* __restrict__ scores, const float* __restrict__ ctx,
    float* __restrict__ attn, float* __restrict__ weighted)
{
    const int b = blockIdx.x, slice = blockIdx.y, t = threadIdx.x;
    const float* sc = scores + b * L_SZ;
    __shared__ float red[256];
    __shared__ float att[128];
    float m = -1e30f;
    for (int l = t; l < L_SZ; l += 256) m = fmaxf(m, sc[l]);
    red[t] = m; __syncthreads();
    for (int s = 128; s > 0; s >>= 1) { if (t < s) red[t] = fmaxf(red[t], red[t + s]); __syncthreads(); }
    m = red[0]; __syncthreads();
    float sum = 0.f;
    for (int l = t; l < L_SZ; l += 256) sum += __expf(sc[l] - m);
    red[t] = sum; __syncthreads();
    for (int s = 128; s > 0; s >>= 1) { if (t < s) red[t] += red[t + s]; __syncthreads(); }
    const float inv = 1.0f / red[0];
    const int l0 = slice * 128;
    if (t < 128) {
        const float av = __expf(sc[l0 + t] - m) * inv;
        att[t] = av;
        attn[b * L_SZ + l0 + t] = av;
    }
    __syncthreads();
    const float* cb = ctx + ((size_t)b * L_SZ + l0) * DIM + t * 4;
    float4 w = make_float4(0.f, 0.f, 0.f, 0.f);
    for (int l = 0; l < 128; ++l) {
        const float a = att[l];
        const float4 c = *(const float4*)(cb + (size_t)l * DIM);
        w.x += a * c.x; w.y += a * c.y; w.z += a * c.z; w.w += a * c.w;
    }
    float* o = weighted + b * DIM + t * 4;
    atomicAdd(o + 0, w.x);
    atomicAdd(o + 1, w.y);
    atomicAdd(o + 2, w.z);
    atomicAdd(o + 3, w.w);
}

extern "C" void kernel_launch(void* const* d_in, const int* in_sizes, int n_in,
                              void* d_out, int out_size, void* d_ws, size_t ws_size,
                              hipStream_t stream) {
    const float* x   = (const float*)d_in[0];   // 32 x 1024
    const float* ctx = (const float*)d_in[1];   // 32 x 2048 x 1024
    const float* Wa  = (const float*)d_in[2];   // 1024 x 2048
    const float* Va  = (const float*)d_in[3];   // 1 x 1024

    float* out      = (float*)d_out;
    float* weighted = out;                      // 32*1024
    float* attn     = out + B_SZ * DIM;         // 32*2048

    float* scores = (float*)d_ws;               // 256 KB
    float* ht     = scores + B_SZ * L_SZ;       // 128 KB

    const size_t base = (size_t)(B_SZ * L_SZ + B_SZ * DIM) * sizeof(float);
    const size_t need = base + (size_t)DIM * DIM * 2            // Wa_s bf16: 2 MB
                      + (size_t)B_SZ * L_SZ * DIM * 2;          // ctx bf16: 128 MB

    if (ws_size >= need) {
        unsigned short* WaB  = (unsigned short*)((char*)d_ws + base);
        unsigned short* ctxB = WaB + (size_t)DIM * DIM;
        pre_kernel<<<CVT_BLOCKS + HT_BLOCKS + WA_BLOCKS, 256, 0, stream>>>(
            x, ctx, Wa, ctxB, WaB, ht, scores, weighted);
        gemm_score_8ph<<<(B_SZ * L_SZ / 256) * (DIM / 256), 512, 0, stream>>>(
            ctxB, WaB, Va, ht, scores);
        post_kernel<<<dim3(B_SZ, 16), 256, 0, stream>>>(scores, ctxB, attn, weighted);
    } else {
        ht_kernel_fb<<<dim3(B_SZ, 16), 256, 0, stream>>>(x, Wa, ht, scores, weighted);
        gemm_score_kernel<<<dim3(DIM / BN, (B_SZ * L_SZ) / BM), 256, 0, stream>>>(
            ctx, Wa, Va, ht, scores);
        post_kernel_fb<<<dim3(B_SZ, 16), 256, 0, stream>>>(scores, ctx, attn, weighted);
    }
}

// Round 3
// 607.518 us; speedup vs baseline: 1.0157x; 1.0157x over previous
//
#include <hip/hip_runtime.h>
#include <hip/hip_bf16.h>
#include <cstdint>
#include <cstddef>

#define DIM 1024
#define B_SZ 32
#define L_SZ 2048

#define BM 128
#define BN 128

// pre_kernel block-range split
#define CVT_BLOCKS 8192
#define HT_BLOCKS  512
#define WA_BLOCKS  512

typedef __attribute__((ext_vector_type(8))) short bf16x8;
typedef __attribute__((ext_vector_type(4))) float floatx4;

static __device__ __forceinline__ unsigned cvt2_bf16_rne(float a, float b) {
    unsigned ua = __builtin_bit_cast(unsigned, a);
    unsigned ub = __builtin_bit_cast(unsigned, b);
    ua = (ua + 0x7FFFu + ((ua >> 16) & 1u)) >> 16;
    ub = (ub + 0x7FFFu + ((ub >> 16) & 1u)) >> 16;
    return ua | (ub << 16);
}

static __device__ __forceinline__ float bf2f(unsigned u16) {
    return __builtin_bit_cast(float, u16 << 16);
}

// tanh(x) = 1 - 2/(e^{2x}+1)
static __device__ __forceinline__ float tanh_fast(float x) {
    float e = __expf(2.0f * x);
    return 1.0f - 2.0f * __builtin_amdgcn_rcpf(e + 1.0f);
}

// async global->LDS, 16B per lane; LDS dest = uniform base + lane*16
static __device__ __forceinline__ void gld_lds16(const void* g, void* lds) {
    __builtin_amdgcn_global_load_lds(
        (const __attribute__((address_space(1))) unsigned int*)g,
        (__attribute__((address_space(3))) unsigned int*)lds,
        16, 0, 0);
}

// ---------------------------------------------------------------------------
// pre_kernel: ONE dispatch for {ctx fp32->bf16, ht_proj, Wa_s fp32->bf16,
// scores zero, weighted zero}. Branch is block-uniform (blockIdx split).
// R3 change: cvt loads are now DENSE per instruction (16B/lane) instead of
// 32B lane stride (which touched every L1 line twice on a 256MB stream);
// stores are dense uint2.
// ---------------------------------------------------------------------------
__global__ __launch_bounds__(256) void pre_kernel(
    const float* __restrict__ x, const float* __restrict__ ctx,
    const float* __restrict__ Wa,
    unsigned short* __restrict__ ctxB, unsigned short* __restrict__ WaB,
    float* __restrict__ ht, float* __restrict__ scores,
    float* __restrict__ weighted)
{
    const int bid = blockIdx.x, t = threadIdx.x;

    if (bid < CVT_BLOCKS) {
        // 16.78M float4 chunks = 4 iters x 8192 blocks x 512 chunks
        const float4* c4 = (const float4*)ctx;
        uint2* o2 = (uint2*)ctxB;
        #pragma unroll
        for (int it = 0; it < 4; ++it) {
            const long g = ((long)it * CVT_BLOCKS + bid) * 512;
            const float4 a = c4[g + t];            // dense: lane stride 16B
            const float4 b = c4[g + 256 + t];      // dense
            o2[g + t]       = make_uint2(cvt2_bf16_rne(a.x, a.y), cvt2_bf16_rne(a.z, a.w));
            o2[g + 256 + t] = make_uint2(cvt2_bf16_rne(b.x, b.y), cvt2_bf16_rne(b.z, b.w));
        }
    } else if (bid < CVT_BLOCKS + HT_BLOCKS) {
        // ---- ht_proj[b][k] = sum_d x[b][d]*Wa[k][d]; + zero scores
        const int lb = bid - CVT_BLOCKS;
        const int gi = lb * 256 + t;
        if (gi < B_SZ * L_SZ) scores[gi] = 0.f;
        const int b = lb >> 4, kb = lb & 15;
        __shared__ float xs[DIM];
        for (int i = t; i < DIM; i += 256) xs[i] = x[b * DIM + i];
        __syncthreads();
        const int wave = t >> 6, lane = t & 63;
        const float4* xs4 = (const float4*)xs;
        for (int kk = 0; kk < 16; ++kk) {
            const int k = kb * 64 + wave * 16 + kk;
            const float4* wr = (const float4*)(Wa + (size_t)k * (2 * DIM));
            float s = 0.f;
            #pragma unroll
            for (int d = 0; d < DIM / 4; d += 64) {
                const float4 w4 = wr[d + lane];
                const float4 x4 = xs4[d + lane];
                s += w4.x * x4.x + w4.y * x4.y + w4.z * x4.z + w4.w * x4.w;
            }
            #pragma unroll
            for (int off = 32; off > 0; off >>= 1) s += __shfl_xor(s, off);
            if (lane == 0) ht[b * DIM + k] = s;
        }
    } else {
        // ---- Wa_s[k][d] = Wa[k][1024+d] -> bf16; + zero weighted
        const int lb = bid - CVT_BLOCKS - HT_BLOCKS;
        const int i = lb * 256 + t;
        if (i < B_SZ * DIM) weighted[i] = 0.f;
        const int k = i >> 7, dc = i & 127;
        const float* s = Wa + (size_t)k * (2 * DIM) + DIM + dc * 8;
        const float4 a = ((const float4*)s)[0];
        const float4 b4 = ((const float4*)s)[1];
        uint4 o;
        o.x = cvt2_bf16_rne(a.x, a.y);
        o.y = cvt2_bf16_rne(a.z, a.w);
        o.z = cvt2_bf16_rne(b4.x, b4.y);
        o.w = cvt2_bf16_rne(b4.z, b4.w);
        ((uint4*)(WaB + (size_t)k * DIM + dc * 8))[0] = o;
    }
}

// ---------------------------------------------------------------------------
// R0-exact bf16 GEMM + fused tanh/Va epilogue (best measured: 189 us, 0 bank
// conflicts) with ONE change: 1D grid + bijective XCD-chunked swizzle so the
// 8 n-tiles sharing an A-panel run consecutively on ONE XCD (R0's 2D grid
// round-robined them across 8 XCDs -> A fetched ~4x, FETCH 530MB). The
// per-K-step vmcnt(0)+barrier drain then waits on L2 hits, not HBM.
// DO NOT replace the DMA staging: direct-global B and inline fp32->bf16 A
// both regressed >1.7x in the earlier session; 8-phase restructures regressed
// in R1/R2 (spills / LDS-MFMA alternation).
// ---------------------------------------------------------------------------
__global__ __launch_bounds__(256) void gemm_score_bf16(
    const unsigned short* __restrict__ A, const unsigned short* __restrict__ Bm,
    const float* __restrict__ Va, const float* __restrict__ ht,
    float* __restrict__ scores)
{
    __shared__ __align__(16) unsigned short As[BM * 64];
    __shared__ __align__(16) unsigned short Bs[BN * 64];
    const int t = threadIdx.x;

    // XCD swizzle: 4096 blocks, 8 XCDs, 512 logical tiles per XCD.
    // logical: m-tile = logical>>3 (owned in contiguous runs per XCD),
    // n-tile = logical&7 (innermost -> A-panel L2-resident across its 8 uses).
    const int bid = blockIdx.x;
    const int logical = (bid & 7) * 512 + (bid >> 3);   // bijective (4096%8==0)
    const int n0 = (logical & 7) * BN;
    const int m0 = (logical >> 3) * BM;

    const int lane = t & 63, wave = t >> 6;
    const int l15 = lane & 15, quad = lane >> 4;
    const int wm = (wave >> 1) * 64, wn = (wave & 1) * 64;

    const int lr = lane >> 3;                 // 0..7 local row
    const int lc = (lane & 7) ^ lr;           // swizzled source chunk
    const size_t aRow = (size_t)(m0 + wave * 32 + lr);
    const size_t bRow = (size_t)(n0 + wave * 32 + lr);

    floatx4 acc[4][4];
    #pragma unroll
    for (int i = 0; i < 4; ++i)
        #pragma unroll
        for (int j = 0; j < 4; ++j) acc[i][j] = (floatx4)0.f;

    for (int k0 = 0; k0 < DIM; k0 += 64) {
        #pragma unroll
        for (int q = 0; q < 4; ++q) {
            gld_lds16(A + (aRow + q * 8) * DIM + k0 + lc * 8,
                      &As[(wave * 32 + q * 8) * 64]);
            gld_lds16(Bm + (bRow + q * 8) * DIM + k0 + lc * 8,
                      &Bs[(wave * 32 + q * 8) * 64]);
        }
        __syncthreads();

        bf16x8 af[2][4], bv[2][4];
        #pragma unroll
        for (int kb = 0; kb < 2; ++kb) {
            #pragma unroll
            for (int i = 0; i < 4; ++i) {
                const int r = wm + i * 16 + l15;
                const int c = (kb * 4 + quad) ^ (r & 7);
                af[kb][i] = *(const bf16x8*)&As[r * 64 + c * 8];
            }
            #pragma unroll
            for (int j = 0; j < 4; ++j) {
                const int r = wn + j * 16 + l15;
                const int c = (kb * 4 + quad) ^ (r & 7);
                bv[kb][j] = *(const bf16x8*)&Bs[r * 64 + c * 8];
            }
        }
        #pragma unroll
        for (int kb = 0; kb < 2; ++kb)
            #pragma unroll
            for (int i = 0; i < 4; ++i)
                #pragma unroll
                for (int j = 0; j < 4; ++j)
                    acc[i][j] = __builtin_amdgcn_mfma_f32_16x16x32_bf16(
                        af[kb][i], bv[kb][j], acc[i][j], 0, 0, 0);
        __syncthreads();
    }

    // epilogue: scores[m] += sum_n tanh(acc + ht[n]) * Va[n]
    // C/D layout: n = lane&15, m = quad*4 + reg
    const int bb = m0 >> 11;
    float htv[4], vav[4];
    #pragma unroll
    for (int j = 0; j < 4; ++j) {
        const int ng = n0 + wn + j * 16 + l15;
        htv[j] = ht[bb * DIM + ng];
        vav[j] = Va[ng];
    }
    #pragma unroll
    for (int i = 0; i < 4; ++i) {
        #pragma unroll
        for (int r = 0; r < 4; ++r) {
            float s = 0.f;
            #pragma unroll
            for (int j = 0; j < 4; ++j)
                s += tanh_fast(acc[i][j][r] + htv[j]) * vav[j];
            s += __shfl_xor(s, 8);
            s += __shfl_xor(s, 4);
            s += __shfl_xor(s, 2);
            s += __shfl_xor(s, 1);
            if (l15 == 0)
                atomicAdd(&scores[m0 + wm + i * 16 + quad * 4 + r], s);
        }
    }
}

// ---------------------------------------------------------------------------
// stats_kernel (NEW): one block per b computes softmax stats ONCE and writes
// the full attn row. Removes the 16x-redundant softmax recompute from post.
// ---------------------------------------------------------------------------
__global__ __launch_bounds__(256) void stats_kernel(
    const float* __restrict__ scores, float* __restrict__ attn)
{
    const int b = blockIdx.x, t = threadIdx.x;
    const float* sc = scores + b * L_SZ;
    __shared__ float red[256];

    float m = -1e30f;
    for (int l = t; l < L_SZ; l += 256) m = fmaxf(m, sc[l]);
    red[t] = m; __syncthreads();
    for (int s = 128; s > 0; s >>= 1) { if (t < s) red[t] = fmaxf(red[t], red[t + s]); __syncthreads(); }
    m = red[0]; __syncthreads();
    float sum = 0.f;
    for (int l = t; l < L_SZ; l += 256) sum += __expf(sc[l] - m);
    red[t] = sum; __syncthreads();
    for (int s = 128; s > 0; s >>= 1) { if (t < s) red[t] += red[t + s]; __syncthreads(); }
    const float inv = 1.0f / red[0];

    for (int l = t; l < L_SZ; l += 256)
        attn[b * L_SZ + l] = __expf(sc[l] - m) * inv;
}

// ---------------------------------------------------------------------------
// post_kernel: pure streaming accumulate of weighted from bf16 ctx using the
// precomputed attn row. No reductions, unroll-4 for load ILP.
// ---------------------------------------------------------------------------
__global__ __launch_bounds__(256) void post_kernel(
    const float* __restrict__ attn, const unsigned short* __restrict__ ctxB,
    float* __restrict__ weighted)
{
    const int b = blockIdx.x, slice = blockIdx.y, t = threadIdx.x;
    __shared__ float att[128];
    const int l0 = slice * 128;
    if (t < 128) att[t] = attn[b * L_SZ + l0 + t];
    __syncthreads();

    const unsigned short* cb = ctxB + ((size_t)b * L_SZ + l0) * DIM + t * 4;
    float a0 = 0.f, a1 = 0.f, a2 = 0.f, a3 = 0.f;
    #pragma unroll 4
    for (int l = 0; l < 128; ++l) {
        const float a = att[l];
        const uint2 v = *(const uint2*)(cb + (size_t)l * DIM);
        a0 += a * bf2f(v.x & 0xFFFFu);
        a1 += a * bf2f(v.x >> 16);
        a2 += a * bf2f(v.y & 0xFFFFu);
        a3 += a * bf2f(v.y >> 16);
    }
    float* o = weighted + b * DIM + t * 4;
    atomicAdd(o + 0, a0);
    atomicAdd(o + 1, a1);
    atomicAdd(o + 2, a2);
    atomicAdd(o + 3, a3);
}

// ---------------------------------------------------------------------------
// fallback path (ws too small): fp32-staging GEMM + separate aux kernels
// ---------------------------------------------------------------------------
#define LDS_STRIDE 40
__global__ __launch_bounds__(256) void ht_kernel_fb(const float* __restrict__ x,
                                                    const float* __restrict__ Wa,
                                                    float* __restrict__ ht,
                                                    float* __restrict__ scores,
                                                    float* __restrict__ weighted) {
    const int b = blockIdx.x, kb = blockIdx.y, t = threadIdx.x;
    const int gidx = (b * 16 + kb) * 256 + t;
    if (gidx < B_SZ * L_SZ) scores[gidx] = 0.f;
    if (gidx < B_SZ * DIM) weighted[gidx] = 0.f;
    __shared__ float xs[DIM];
    for (int i = t; i < DIM; i += 256) xs[i] = x[b * DIM + i];
    __syncthreads();
    const int wave = t >> 6, lane = t & 63;
    for (int kk = 0; kk < 16; ++kk) {
        const int k = kb * 64 + wave * 16 + kk;
        const float* wr = Wa + (size_t)k * (2 * DIM);
        float s = 0.f;
        #pragma unroll
        for (int d = 0; d < DIM; d += 64) s += xs[d + lane] * wr[d + lane];
        #pragma unroll
        for (int off = 32; off > 0; off >>= 1) s += __shfl_xor(s, off);
        if (lane == 0) ht[b * DIM + k] = s;
    }
}

__global__ __launch_bounds__(256, 2) void gemm_score_kernel(
    const float* __restrict__ ctx, const float* __restrict__ Wa,
    const float* __restrict__ Va, const float* __restrict__ ht,
    float* __restrict__ scores)
{
    __shared__ unsigned short As[BM * LDS_STRIDE];
    __shared__ unsigned short Bs[BN * LDS_STRIDE];
    const int t = threadIdx.x;
    const int n0 = blockIdx.x * BN;
    const int m0 = blockIdx.y * BM;
    const int lane = t & 63, wave = t >> 6;
    const int l15 = lane & 15, quad = lane >> 4;
    const int wm = (wave >> 1) * 64, wn = (wave & 1) * 64;
    const int srow = t >> 3;
    const int scol = (t & 7) * 4;
    const float* aBase = ctx + (size_t)(m0 + srow) * DIM + scol;
    const float* bBase = Wa + (size_t)(n0 + srow) * (2 * DIM) + DIM + scol;

    floatx4 acc[4][4];
    #pragma unroll
    for (int i = 0; i < 4; ++i)
        #pragma unroll
        for (int j = 0; j < 4; ++j) acc[i][j] = (floatx4)0.f;

    for (int k0 = 0; k0 < DIM; k0 += 32) {
        __syncthreads();
        #pragma unroll
        for (int r = 0; r < 4; ++r) {
            const float4 va = *(const float4*)(aBase + (size_t)(r * 32) * DIM + k0);
            const float4 vb = *(const float4*)(bBase + (size_t)(r * 32) * (2 * DIM) + k0);
            *(uint2*)&As[(srow + r * 32) * LDS_STRIDE + scol] =
                make_uint2(cvt2_bf16_rne(va.x, va.y), cvt2_bf16_rne(va.z, va.w));
            *(uint2*)&Bs[(srow + r * 32) * LDS_STRIDE + scol] =
                make_uint2(cvt2_bf16_rne(vb.x, vb.y), cvt2_bf16_rne(vb.z, vb.w));
        }
        __syncthreads();
        bf16x8 af[4], bfr[4];
        #pragma unroll
        for (int i = 0; i < 4; ++i)
            af[i] = *(const bf16x8*)&As[(wm + i * 16 + l15) * LDS_STRIDE + quad * 8];
        #pragma unroll
        for (int j = 0; j < 4; ++j)
            bfr[j] = *(const bf16x8*)&Bs[(wn + j * 16 + l15) * LDS_STRIDE + quad * 8];
        #pragma unroll
        for (int i = 0; i < 4; ++i)
            #pragma unroll
            for (int j = 0; j < 4; ++j)
                acc[i][j] = __builtin_amdgcn_mfma_f32_16x16x32_bf16(af[i], bfr[j], acc[i][j], 0, 0, 0);
    }
    const int bb = m0 >> 11;
    float htv[4], vav[4];
    #pragma unroll
    for (int j = 0; j < 4; ++j) {
        const int ng = n0 + wn + j * 16 + l15;
        htv[j] = ht[bb * DIM + ng];
        vav[j] = Va[ng];
    }
    #pragma unroll
    for (int i = 0; i < 4; ++i) {
        #pragma unroll
        for (int r = 0; r < 4; ++r) {
            float s = 0.f;
            #pragma unroll
            for (int j = 0; j < 4; ++j)
                s += tanh_fast(acc[i][j][r] + htv[j]) * vav[j];
            s += __shfl_xor(s, 8);
            s += __shfl_xor(s, 4);
            s += __shfl_xor(s, 2);
            s += __shfl_xor(s, 1);
            if (l15 == 0)
                atomicAdd(&scores[m0 + wm + i * 16 + quad * 4 + r], s);
        }
    }
}

__global__ __launch_bounds__(256) void post_kernel_fb(
    const float* __restrict__ scores, const float* __restrict__ ctx,
    float* __restrict__ attn, float* __restrict__ weighted)
{
    const int b = blockIdx.x, slice = blockIdx.y, t = threadIdx.x;
    const float* sc = scores + b * L_SZ;
    __shared__ float red[256];
    __shared__ float att[128];
    float m = -1e30f;
    for (int l = t; l < L_SZ; l += 256) m = fmaxf(m, sc[l]);
    red[t] = m; __syncthreads();
    for (int s = 128; s > 0; s >>= 1) { if (t < s) red[t] = fmaxf(red[t], red[t + s]); __syncthreads(); }
    m = red[0]; __syncthreads();
    float sum = 0.f;
    for (int l = t; l < L_SZ; l += 256) sum += __expf(sc[l] - m);
    red[t] = sum; __syncthreads();
    for (int s = 128; s > 0; s >>= 1) { if (t < s) red[t] += red[t + s]; __syncthreads(); }
    const float inv = 1.0f / red[0];
    const int l0 = slice * 128;
    if (t < 128) {
        const float av = __expf(sc[l0 + t] - m) * inv;
        att[t] = av;
        attn[b * L_SZ + l0 + t] = av;
    }
    __syncthreads();
    const float* cb = ctx + ((size_t)b * L_SZ + l0) * DIM + t * 4;
    float4 w = make_float4(0.f, 0.f, 0.f, 0.f);
    for (int l = 0; l < 128; ++l) {
        const float a = att[l];
        const float4 c = *(const float4*)(cb + (size_t)l * DIM);
        w.x += a * c.x; w.y += a * c.y; w.z += a * c.z; w.w += a * c.w;
    }
    float* o = weighted + b * DIM + t * 4;
    atomicAdd(o + 0, w.x);
    atomicAdd(o + 1, w.y);
    atomicAdd(o + 2, w.z);
    atomicAdd(o + 3, w.w);
}

extern "C" void kernel_launch(void* const* d_in, const int* in_sizes, int n_in,
                              void* d_out, int out_size, void* d_ws, size_t ws_size,
                              hipStream_t stream) {
    const float* x   = (const float*)d_in[0];   // 32 x 1024
    const float* ctx = (const float*)d_in[1];   // 32 x 2048 x 1024
    const float* Wa  = (const float*)d_in[2];   // 1024 x 2048
    const float* Va  = (const float*)d_in[3];   // 1 x 1024

    float* out      = (float*)d_out;
    float* weighted = out;                      // 32*1024
    float* attn     = out + B_SZ * DIM;         // 32*2048

    float* scores = (float*)d_ws;               // 256 KB
    float* ht     = scores + B_SZ * L_SZ;       // 128 KB

    const size_t base = (size_t)(B_SZ * L_SZ + B_SZ * DIM) * sizeof(float);
    const size_t need = base + (size_t)DIM * DIM * 2            // Wa_s bf16: 2 MB
                      + (size_t)B_SZ * L_SZ * DIM * 2;          // ctx bf16: 128 MB

    if (ws_size >= need) {
        unsigned short* WaB  = (unsigned short*)((char*)d_ws + base);
        unsigned short* ctxB = WaB + (size_t)DIM * DIM;
        pre_kernel<<<CVT_BLOCKS + HT_BLOCKS + WA_BLOCKS, 256, 0, stream>>>(
            x, ctx, Wa, ctxB, WaB, ht, scores, weighted);
        gemm_score_bf16<<<(DIM / BN) * ((B_SZ * L_SZ) / BM), 256, 0, stream>>>(
            ctxB, WaB, Va, ht, scores);
        stats_kernel<<<B_SZ, 256, 0, stream>>>(scores, attn);
        post_kernel<<<dim3(B_SZ, 16), 256, 0, stream>>>(attn, ctxB, weighted);
    } else {
        ht_kernel_fb<<<dim3(B_SZ, 16), 256, 0, stream>>>(x, Wa, ht, scores, weighted);
        gemm_score_kernel<<<dim3(DIM / BN, (B_SZ * L_SZ) / BM), 256, 0, stream>>>(
            ctx, Wa, Va, ht, scores);
        post_kernel_fb<<<dim3(B_SZ, 16), 256, 0, stream>>>(scores, ctx, attn, weighted);
    }
}